// Round 1
// baseline (2404.286 us; speedup 1.0000x reference)
//
#include <hip/hip_runtime.h>
#include <stdint.h>

#define AA 9
#define HH 384
#define WW 384
#define NN (AA*HH*WW)          // 1327104
#define PRE_NMS_ 6000
#define POST_NMS_ 300
#define NBUCK (1u<<20)
#define LB_CAP 4096
#define NP 6016                 // 6000 padded to multiple of 64

// ---------- helpers ----------

// Map float score -> uint32 key that is ASCENDING when score is DESCENDING.
static __device__ __forceinline__ uint32_t score_key(float s) {
  uint32_t b = __float_as_uint(s);
  uint32_t u = b ^ (((int32_t)b < 0) ? 0xFFFFFFFFu : 0x80000000u); // ascending map
  return ~u;                                                        // descending map
}

// Sortable-ascending map for y2 (used in argmax).
static __device__ __forceinline__ uint32_t f2s(float v) {
  uint32_t b = __float_as_uint(v);
  return b ^ (((int32_t)b < 0) ? 0xFFFFFFFFu : 0x80000000u);
}

// Exact replication of reference box decode + _clip_boxes + keep mask.
static __device__ __forceinline__ void compute_box(float4 an, float4 de,
    float& x1, float& y1, float& wc, float& hc, bool& keep) {
  float bx = fmaxf(an.x + de.x, 0.0f);
  float by = fmaxf(an.y + de.y, 0.0f);
  float bw = fmaxf(an.z + de.z, 0.0f);
  float bh = fmaxf(an.w + de.w, 0.0f);
  float x2 = bx + bw - 1.0f;     // uses pre-min x1 (matches reference order)
  float y2 = by + bh - 1.0f;
  x1 = fminf(bx, 383.0f);
  y1 = fminf(by, 383.0f);
  x2 = fminf(x2, 383.0f);
  y2 = fminf(y2, 383.0f);
  wc = x2 - x1 + 1.0f;
  hc = y2 - y1 + 1.0f;
  keep = (wc >= 2.0f) && (hc >= 2.0f);
}

// ---------- K1: histogram of descending score keys ----------
__global__ void k_hist(const float* __restrict__ scores,
                       const float4* __restrict__ deltas,
                       const float4* __restrict__ anchors,
                       uint32_t* __restrict__ hist) {
  int i = blockIdx.x * blockDim.x + threadIdx.x;
  if (i >= NN) return;
  float x1, y1, wc, hc; bool keep;
  compute_box(anchors[i], deltas[i], x1, y1, wc, hc, keep);
  uint32_t d = keep ? score_key(scores[i]) : 0xFF800000u;  // key(-inf)
  atomicAdd(&hist[d >> 12], 1u);
}

// ---------- K2: find threshold bucket B* and C0 = count strictly above it ----------
// ctr[0]=lcnt ctr[1]=bcnt ctr[2]=B* ctr[3]=C0
__global__ __launch_bounds__(1024) void k_thresh(const uint32_t* __restrict__ hist,
                                                 uint32_t* __restrict__ ctr) {
  __shared__ uint32_t psum[1024];
  __shared__ uint32_t gbuf[1024];
  __shared__ uint32_t gsel, cbase;
  int t = threadIdx.x;
  const uint4* hv = (const uint4*)(hist + (size_t)t * 1024);
  uint32_t s = 0;
  for (int j = 0; j < 256; ++j) { uint4 v = hv[j]; s += v.x + v.y + v.z + v.w; }
  psum[t] = s;
  __syncthreads();
  if (t == 0) {
    uint32_t cum = 0; uint32_t g = 1023;
    for (int i = 0; i < 1024; ++i) {
      if (cum + psum[i] >= PRE_NMS_) { g = i; break; }
      cum += psum[i];
    }
    gsel = g; cbase = cum;
  }
  __syncthreads();
  gbuf[t] = hist[gsel * 1024 + t];
  __syncthreads();
  if (t == 0) {
    uint32_t cum = cbase;
    uint32_t Bs = gsel * 1024 + 1023;
    for (int i = 0; i < 1024; ++i) {
      if (cum + gbuf[i] >= PRE_NMS_) { Bs = gsel * 1024 + i; break; }
      cum += gbuf[i];
    }
    ctr[2] = Bs; ctr[3] = cum;
  }
}

// ---------- K3: gather candidates (buckets < B* definite, == B* boundary) ----------
__global__ void k_gather(const float* __restrict__ scores,
                         const float4* __restrict__ deltas,
                         const float4* __restrict__ anchors,
                         uint32_t* __restrict__ ctr,
                         uint64_t* __restrict__ L,
                         uint64_t* __restrict__ Lb) {
  int i = blockIdx.x * blockDim.x + threadIdx.x;
  if (i >= NN) return;
  float x1, y1, wc, hc; bool keep;
  compute_box(anchors[i], deltas[i], x1, y1, wc, hc, keep);
  uint32_t d = keep ? score_key(scores[i]) : 0xFF800000u;
  uint32_t bk = d >> 12;
  uint32_t Bs = ctr[2];
  if (bk > Bs) return;
  uint64_t key = ((uint64_t)d << 32) | (uint32_t)i;
  if (bk < Bs) {
    uint32_t p = atomicAdd(&ctr[0], 1u);
    if (p < PRE_NMS_) L[p] = key;          // p < 6000 guaranteed (C0 < 6000)
  } else {
    uint32_t p = atomicAdd(&ctr[1], 1u);
    if (p < LB_CAP) Lb[p] = key;
  }
}

// ---------- K4: sort boundary bucket, append T=6000-C0 smallest (d,idx) to L ----------
__global__ __launch_bounds__(1024) void k_boundary(const uint32_t* __restrict__ ctr,
                                                   uint64_t* __restrict__ L,
                                                   const uint64_t* __restrict__ Lb) {
  __shared__ uint64_t keys[LB_CAP];
  int t = threadIdx.x;
  uint32_t Cb = ctr[1]; if (Cb > LB_CAP) Cb = LB_CAP;
  uint32_t C0 = ctr[3];
  uint32_t T = PRE_NMS_ - C0;
  uint32_t n = 2; while (n < Cb) n <<= 1;   // pow2 >= Cb, <= LB_CAP
  for (uint32_t j = t; j < n; j += 1024) keys[j] = (j < Cb) ? Lb[j] : ~0ULL;
  __syncthreads();
  for (uint32_t k = 2; k <= n; k <<= 1) {
    for (uint32_t jj = k >> 1; jj > 0; jj >>= 1) {
      for (uint32_t i = t; i < n; i += 1024) {
        uint32_t l = i ^ jj;
        if (l > i) {
          uint64_t a = keys[i], b = keys[l];
          bool up = ((i & k) == 0);
          if (up ? (a > b) : (a < b)) { keys[i] = b; keys[l] = a; }
        }
      }
      __syncthreads();
    }
  }
  for (uint32_t j = t; j < T; j += 1024) L[C0 + j] = (j < n) ? keys[j] : ~0ULL;
}

// ---------- K5: NMS entirely in LDS, 96-bit argmax (y2, ~d, ~idx) ----------
__global__ __launch_bounds__(1024) void k_nms(const uint64_t* __restrict__ L,
                                              const float4* __restrict__ deltas,
                                              const float4* __restrict__ anchors,
                                              float* __restrict__ out) {
  __shared__ float lx1[NP], ly1[NP], lw[NP], lh[NP];
  __shared__ uint32_t lnd[NP], lni[NP];
  __shared__ unsigned char lval[NP];
  __shared__ uint64_t whi[16], wlo[16];
  __shared__ uint64_t bhi_s, blo_s;
  int t = threadIdx.x;

  for (int j = t; j < NP; j += 1024) {
    if (j < PRE_NMS_) {
      uint64_t key = L[j];
      uint32_t d = (uint32_t)(key >> 32);
      uint32_t idx = (uint32_t)key;
      float x1, y1, wc, hc; bool keep;
      float4 an = anchors[idx], de = deltas[idx];
      compute_box(an, de, x1, y1, wc, hc, keep);
      lx1[j] = x1; ly1[j] = y1; lw[j] = wc; lh[j] = hc;
      lnd[j] = ~d; lni[j] = ~idx;
      lval[j] = (d < 0xFF800000u) ? 1 : 0;   // finite masked score only
    } else {
      lx1[j] = 0.f; ly1[j] = 0.f; lw[j] = 0.f; lh[j] = 0.f;
      lnd[j] = 0; lni[j] = 0; lval[j] = 0;
    }
  }
  __syncthreads();

  int cnt = 0;
  for (; cnt < POST_NMS_; ++cnt) {
    // --- argmax over (y2 asc, ~d asc, ~idx asc) among valid ---
    uint64_t bhi = 0, blo = 0;
    for (int j = t; j < NP; j += 1024) {
      if (!lval[j]) continue;
      float y2 = ly1[j] + lh[j] - 1.0f;
      uint64_t hi = ((uint64_t)f2s(y2) << 32) | (uint64_t)lnd[j];
      uint64_t lo = ((uint64_t)lni[j] << 16) | (uint32_t)j;
      if (hi > bhi || (hi == bhi && lo > blo)) { bhi = hi; blo = lo; }
    }
    for (int off = 32; off > 0; off >>= 1) {
      uint64_t ohi = __shfl_xor(bhi, off);
      uint64_t olo = __shfl_xor(blo, off);
      if (ohi > bhi || (ohi == bhi && olo > blo)) { bhi = ohi; blo = olo; }
    }
    int wid = t >> 6, lane = t & 63;
    if (lane == 0) { whi[wid] = bhi; wlo[wid] = blo; }
    __syncthreads();
    if (wid == 0) {
      bhi = (lane < 16) ? whi[lane] : 0;
      blo = (lane < 16) ? wlo[lane] : 0;
      for (int off = 8; off > 0; off >>= 1) {
        uint64_t ohi = __shfl_xor(bhi, off);
        uint64_t olo = __shfl_xor(blo, off);
        if (ohi > bhi || (ohi == bhi && olo > blo)) { bhi = ohi; blo = olo; }
      }
      if (lane == 0) { bhi_s = bhi; blo_s = blo; }
    }
    __syncthreads();
    if (bhi_s == 0) break;                    // no valid left (uniform)
    int ind = (int)(blo_s & 0xFFFFu);

    float sx1 = lx1[ind], sy1 = ly1[ind], sw = lw[ind], sh = lh[ind];
    float sx2 = sx1 + sw - 1.0f, sy2 = sy1 + sh - 1.0f;
    if (t == 0) {
      out[cnt * 4 + 0] = sx1; out[cnt * 4 + 1] = sy1;
      out[cnt * 4 + 2] = sw;  out[cnt * 4 + 3] = sh;
      lval[ind] = 0;
    }
    // --- suppression: keep iff inter/area_j < 0.7 (IEEE divide, NaN suppresses) ---
    for (int j = t; j < NP; j += 1024) {
      if (!lval[j]) continue;
      float x1j = lx1[j], y1j = ly1[j], wj = lw[j], hj = lh[j];
      float x2j = x1j + wj - 1.0f, y2j = y1j + hj - 1.0f;
      float xx1 = fmaxf(x1j, sx1), yy1 = fmaxf(y1j, sy1);
      float xx2 = fminf(x2j, sx2), yy2 = fminf(y2j, sy2);
      float iw = fmaxf(xx2 - xx1 + 1.0f, 0.0f);
      float ih = fmaxf(yy2 - yy1 + 1.0f, 0.0f);
      float inter = iw * ih;
      float area = wj * hj;
      float ratio = inter / area;
      if (!(ratio < 0.7f)) lval[j] = 0;
    }
    __syncthreads();
  }

  // zero-fill remaining output rows
  for (int j = t; j < (POST_NMS_ - cnt) * 4; j += 1024) out[cnt * 4 + j] = 0.0f;
}

// ---------- launch ----------
extern "C" void kernel_launch(void* const* d_in, const int* in_sizes, int n_in,
                              void* d_out, int out_size, void* d_ws, size_t ws_size,
                              hipStream_t stream) {
  const float*  scores  = (const float*)d_in[0];
  const float4* deltas  = (const float4*)d_in[1];
  const float4* anchors = (const float4*)d_in[2];
  float* out = (float*)d_out;

  uint8_t* w8 = (uint8_t*)d_ws;
  uint32_t* hist = (uint32_t*)w8;                                   // 4 MiB
  uint32_t* ctr  = (uint32_t*)(w8 + (size_t)NBUCK * 4);             // 16 B
  uint64_t* L    = (uint64_t*)(w8 + (size_t)NBUCK * 4 + 256);       // 48000 B
  uint64_t* Lb   = (uint64_t*)(w8 + (size_t)NBUCK * 4 + 256 + (size_t)PRE_NMS_ * 8); // 32768 B

  hipMemsetAsync(d_ws, 0, (size_t)NBUCK * 4 + 16, stream);

  int blocks = (NN + 255) / 256;
  k_hist  <<<blocks, 256, 0, stream>>>(scores, deltas, anchors, hist);
  k_thresh<<<1, 1024, 0, stream>>>(hist, ctr);
  k_gather<<<blocks, 256, 0, stream>>>(scores, deltas, anchors, ctr, L, Lb);
  k_boundary<<<1, 1024, 0, stream>>>(ctr, L, Lb);
  k_nms   <<<1, 1024, 0, stream>>>(L, deltas, anchors, out);
}

// Round 2
// 1843.310 us; speedup vs baseline: 1.3043x; 1.3043x over previous
//
#include <hip/hip_runtime.h>
#include <stdint.h>

#define AA 9
#define HH 384
#define WW 384
#define NN (AA*HH*WW)          // 1327104
#define PRE_NMS_ 6000
#define POST_NMS_ 300
#define NBUCK (1u<<20)
#define LB_CAP 4096
#define CPT 6                   // candidates per thread (6*1024 = 6144 >= 6000)

// ---------- helpers ----------

// Map float score -> uint32 key that is ASCENDING when score is DESCENDING.
static __device__ __forceinline__ uint32_t score_key(float s) {
  uint32_t b = __float_as_uint(s);
  uint32_t u = b ^ (((int32_t)b < 0) ? 0xFFFFFFFFu : 0x80000000u); // ascending map
  return ~u;                                                        // descending map
}

// Sortable-ascending map for floats (used on y2 in the argmax key).
static __device__ __forceinline__ uint32_t f2s(float v) {
  uint32_t b = __float_as_uint(v);
  return b ^ (((int32_t)b < 0) ? 0xFFFFFFFFu : 0x80000000u);
}

// Exact replication of reference box decode + _clip_boxes + keep mask.
static __device__ __forceinline__ void compute_box(float4 an, float4 de,
    float& x1, float& y1, float& wc, float& hc, bool& keep) {
  float bx = fmaxf(an.x + de.x, 0.0f);
  float by = fmaxf(an.y + de.y, 0.0f);
  float bw = fmaxf(an.z + de.z, 0.0f);
  float bh = fmaxf(an.w + de.w, 0.0f);
  float x2 = bx + bw - 1.0f;     // uses pre-min x1 (matches reference order)
  float y2 = by + bh - 1.0f;
  x1 = fminf(bx, 383.0f);
  y1 = fminf(by, 383.0f);
  x2 = fminf(x2, 383.0f);
  y2 = fminf(y2, 383.0f);
  wc = x2 - x1 + 1.0f;
  hc = y2 - y1 + 1.0f;
  keep = (wc >= 2.0f) && (hc >= 2.0f);
}

// ---------- K1: histogram of descending score keys ----------
__global__ void k_hist(const float* __restrict__ scores,
                       const float4* __restrict__ deltas,
                       const float4* __restrict__ anchors,
                       uint32_t* __restrict__ hist) {
  int i = blockIdx.x * blockDim.x + threadIdx.x;
  if (i >= NN) return;
  float x1, y1, wc, hc; bool keep;
  compute_box(anchors[i], deltas[i], x1, y1, wc, hc, keep);
  uint32_t d = keep ? score_key(scores[i]) : 0xFF800000u;  // key(-inf)
  atomicAdd(&hist[d >> 12], 1u);
}

// ---------- K2a: group sums of the histogram (whole-GPU 4MB read) ----------
__global__ __launch_bounds__(256) void k_psum(const uint32_t* __restrict__ hist,
                                              uint32_t* __restrict__ psum) {
  __shared__ uint32_t red[256];
  int b = blockIdx.x, t = threadIdx.x;
  const uint4* hv = (const uint4*)(hist + (size_t)b * 1024);
  uint4 v = hv[t];
  red[t] = v.x + v.y + v.z + v.w;
  __syncthreads();
  for (int off = 128; off; off >>= 1) {
    if (t < off) red[t] += red[t + off];
    __syncthreads();
  }
  if (t == 0) psum[b] = red[0];
}

// ---------- K2b: two-level parallel scan -> threshold bucket B*, C0 ----------
// ctr[0]=lcnt ctr[1]=bcnt ctr[2]=B* ctr[3]=C0
__global__ __launch_bounds__(1024) void k_pick(const uint32_t* __restrict__ hist,
                                               const uint32_t* __restrict__ psum,
                                               uint32_t* __restrict__ ctr) {
  __shared__ uint32_t sc[1024];
  __shared__ uint32_t gsel, cbase;
  int t = threadIdx.x;

  // level 1: scan group sums
  uint32_t v = psum[t];
  sc[t] = v; __syncthreads();
  uint32_t acc = v;
  for (int off = 1; off < 1024; off <<= 1) {
    uint32_t u = (t >= off) ? sc[t - off] : 0;
    __syncthreads();
    acc += u; sc[t] = acc;
    __syncthreads();
  }
  uint32_t excl = acc - v;
  if (excl < PRE_NMS_ && acc >= PRE_NMS_) { gsel = t; cbase = excl; }
  __syncthreads();
  uint32_t g = gsel, cb = cbase;
  __syncthreads();

  // level 2: scan the selected group's 1024 buckets
  v = hist[(size_t)g * 1024 + t];
  sc[t] = v; __syncthreads();
  acc = v;
  for (int off = 1; off < 1024; off <<= 1) {
    uint32_t u = (t >= off) ? sc[t - off] : 0;
    __syncthreads();
    acc += u; sc[t] = acc;
    __syncthreads();
  }
  excl = cb + (acc - v);
  uint32_t incl = cb + acc;
  if (excl < PRE_NMS_ && incl >= PRE_NMS_) {
    ctr[2] = g * 1024 + t;   // B*
    ctr[3] = excl;           // C0 = count strictly above B*
  }
}

// ---------- K3: gather candidates (buckets < B* definite, == B* boundary) ----------
__global__ void k_gather(const float* __restrict__ scores,
                         const float4* __restrict__ deltas,
                         const float4* __restrict__ anchors,
                         uint32_t* __restrict__ ctr,
                         uint64_t* __restrict__ L,
                         uint64_t* __restrict__ Lb) {
  int i = blockIdx.x * blockDim.x + threadIdx.x;
  if (i >= NN) return;
  float x1, y1, wc, hc; bool keep;
  compute_box(anchors[i], deltas[i], x1, y1, wc, hc, keep);
  uint32_t d = keep ? score_key(scores[i]) : 0xFF800000u;
  uint32_t bk = d >> 12;
  uint32_t Bs = ctr[2];
  if (bk > Bs) return;
  uint64_t key = ((uint64_t)d << 32) | (uint32_t)i;
  if (bk < Bs) {
    uint32_t p = atomicAdd(&ctr[0], 1u);
    if (p < PRE_NMS_) L[p] = key;          // p < 6000 guaranteed (C0 < 6000)
  } else {
    uint32_t p = atomicAdd(&ctr[1], 1u);
    if (p < LB_CAP) Lb[p] = key;
  }
}

// ---------- K4: sort boundary bucket, append T=6000-C0 smallest (d,idx) to L ----------
__global__ __launch_bounds__(1024) void k_boundary(const uint32_t* __restrict__ ctr,
                                                   uint64_t* __restrict__ L,
                                                   const uint64_t* __restrict__ Lb) {
  __shared__ uint64_t keys[LB_CAP];
  int t = threadIdx.x;
  uint32_t Cb = ctr[1]; if (Cb > LB_CAP) Cb = LB_CAP;
  uint32_t C0 = ctr[3];
  uint32_t T = PRE_NMS_ - C0;
  uint32_t n = 2; while (n < Cb) n <<= 1;   // pow2 >= Cb, <= LB_CAP
  for (uint32_t j = t; j < n; j += 1024) keys[j] = (j < Cb) ? Lb[j] : ~0ULL;
  __syncthreads();
  for (uint32_t k = 2; k <= n; k <<= 1) {
    for (uint32_t jj = k >> 1; jj > 0; jj >>= 1) {
      for (uint32_t i = t; i < n; i += 1024) {
        uint32_t l = i ^ jj;
        if (l > i) {
          uint64_t a = keys[i], b = keys[l];
          bool up = ((i & k) == 0);
          if (up ? (a > b) : (a < b)) { keys[i] = b; keys[l] = a; }
        }
      }
      __syncthreads();
    }
  }
  for (uint32_t j = t; j < T; j += 1024) L[C0 + j] = (j < n) ? keys[j] : ~0ULL;
}

// ---------- K5: register-resident NMS, 96-bit argmax (y2, ~d, ~idx) ----------
__global__ __launch_bounds__(1024) void k_nms(const uint64_t* __restrict__ L,
                                              const float4* __restrict__ deltas,
                                              const float4* __restrict__ anchors,
                                              float* __restrict__ out) {
  __shared__ uint64_t whi[16];
  __shared__ uint32_t wlo[16];
  __shared__ uint64_t bhi_s;
  __shared__ uint32_t blo_s;
  __shared__ float sbox[4];      // sx1, sy1, sx2, sy2
  int t = threadIdx.x;

  float cx1[CPT], cy1[CPT], cx2[CPT], cy2[CPT], car[CPT];
  uint64_t chi[CPT];
  uint32_t clo[CPT];
  unsigned vmask = 0;

  #pragma unroll
  for (int c = 0; c < CPT; ++c) {
    int j = c * 1024 + t;
    uint64_t key = (j < PRE_NMS_) ? L[j] : ~0ULL;
    uint32_t d = (uint32_t)(key >> 32);
    uint32_t idx = (uint32_t)key;
    if (d < 0xFF800000u) {                  // finite masked score only
      float x1, y1, wc, hc; bool keep;
      float4 an = anchors[idx], de = deltas[idx];
      compute_box(an, de, x1, y1, wc, hc, keep);
      cx1[c] = x1; cy1[c] = y1;
      cx2[c] = x1 + wc - 1.0f; cy2[c] = y1 + hc - 1.0f;
      car[c] = wc * hc;
      chi[c] = ((uint64_t)f2s(cy2[c]) << 32) | (uint32_t)(~d);
      clo[c] = ~idx;
      vmask |= (1u << c);
    } else {
      cx1[c] = cy1[c] = cx2[c] = cy2[c] = car[c] = 0.0f;
      chi[c] = 0; clo[c] = 0;
    }
  }

  int cnt = 0;
  for (; cnt < POST_NMS_; ++cnt) {
    // --- local argmax among own valid candidates ---
    uint64_t bhi = 0; uint32_t blo = 0;
    if (vmask) {
      #pragma unroll
      for (int c = 0; c < CPT; ++c) {
        bool v = (vmask >> c) & 1u;
        if (v && (chi[c] > bhi || (chi[c] == bhi && clo[c] > blo))) {
          bhi = chi[c]; blo = clo[c];
        }
      }
    }
    // --- wave reduce (64 lanes) ---
    #pragma unroll
    for (int off = 32; off > 0; off >>= 1) {
      uint64_t ohi = __shfl_xor((unsigned long long)bhi, off);
      uint32_t olo = __shfl_xor(blo, off);
      if (ohi > bhi || (ohi == bhi && olo > blo)) { bhi = ohi; blo = olo; }
    }
    int wid = t >> 6;
    if ((t & 63) == 0) { whi[wid] = bhi; wlo[wid] = blo; }
    __syncthreads();                                   // A
    if (t < 64) {
      bhi = (t < 16) ? whi[t] : 0;
      blo = (t < 16) ? wlo[t] : 0;
      #pragma unroll
      for (int off = 8; off > 0; off >>= 1) {
        uint64_t ohi = __shfl_xor((unsigned long long)bhi, off);
        uint32_t olo = __shfl_xor(blo, off);
        if (ohi > bhi || (ohi == bhi && olo > blo)) { bhi = ohi; blo = olo; }
      }
      if (t == 0) { bhi_s = bhi; blo_s = blo; }
    }
    __syncthreads();                                   // B
    uint64_t Bhi = bhi_s; uint32_t Blo = blo_s;
    if (Bhi == 0) break;                               // no valid left (uniform)

    // --- winner broadcasts its box, writes output row, clears itself ---
    if (vmask) {
      #pragma unroll
      for (int c = 0; c < CPT; ++c) {
        if (((vmask >> c) & 1u) && chi[c] == Bhi && clo[c] == Blo) {
          vmask &= ~(1u << c);
          sbox[0] = cx1[c]; sbox[1] = cy1[c];
          sbox[2] = cx2[c]; sbox[3] = cy2[c];
          out[cnt * 4 + 0] = cx1[c];
          out[cnt * 4 + 1] = cy1[c];
          out[cnt * 4 + 2] = cx2[c] - cx1[c] + 1.0f;
          out[cnt * 4 + 3] = cy2[c] - cy1[c] + 1.0f;
        }
      }
    }
    __syncthreads();                                   // C
    float sx1 = sbox[0], sy1 = sbox[1], sx2 = sbox[2], sy2 = sbox[3];

    // --- suppression: keep iff inter/area_j < 0.7 (IEEE divide) ---
    if (vmask) {
      #pragma unroll
      for (int c = 0; c < CPT; ++c) {
        if ((vmask >> c) & 1u) {
          float xx1 = fmaxf(cx1[c], sx1), yy1 = fmaxf(cy1[c], sy1);
          float xx2 = fminf(cx2[c], sx2), yy2 = fminf(cy2[c], sy2);
          float iw = fmaxf(xx2 - xx1 + 1.0f, 0.0f);
          float ih = fmaxf(yy2 - yy1 + 1.0f, 0.0f);
          float ratio = (iw * ih) / car[c];
          if (!(ratio < 0.7f)) vmask &= ~(1u << c);
        }
      }
    }
    // no barrier needed: next iteration's A/B barriers order sbox reuse
  }

  // zero-fill remaining output rows
  for (int j = t; j < (POST_NMS_ - cnt) * 4; j += 1024) out[cnt * 4 + j] = 0.0f;
}

// ---------- launch ----------
extern "C" void kernel_launch(void* const* d_in, const int* in_sizes, int n_in,
                              void* d_out, int out_size, void* d_ws, size_t ws_size,
                              hipStream_t stream) {
  const float*  scores  = (const float*)d_in[0];
  const float4* deltas  = (const float4*)d_in[1];
  const float4* anchors = (const float4*)d_in[2];
  float* out = (float*)d_out;

  uint8_t* w8 = (uint8_t*)d_ws;
  uint32_t* hist = (uint32_t*)w8;                                   // 4 MiB
  uint32_t* ctr  = (uint32_t*)(w8 + (size_t)NBUCK * 4);             // 16 B (256 pad)
  uint64_t* L    = (uint64_t*)(w8 + (size_t)NBUCK * 4 + 256);       // 48000 B
  uint64_t* Lb   = (uint64_t*)(w8 + (size_t)NBUCK * 4 + 256 + (size_t)PRE_NMS_ * 8); // 32 KiB
  uint32_t* psum = (uint32_t*)(w8 + (size_t)NBUCK * 4 + 256 + (size_t)PRE_NMS_ * 8
                                  + (size_t)LB_CAP * 8);            // 4 KiB

  hipMemsetAsync(d_ws, 0, (size_t)NBUCK * 4 + 16, stream);

  int blocks = (NN + 255) / 256;
  k_hist    <<<blocks, 256, 0, stream>>>(scores, deltas, anchors, hist);
  k_psum    <<<1024, 256, 0, stream>>>(hist, psum);
  k_pick    <<<1, 1024, 0, stream>>>(hist, psum, ctr);
  k_gather  <<<blocks, 256, 0, stream>>>(scores, deltas, anchors, ctr, L, Lb);
  k_boundary<<<1, 1024, 0, stream>>>(ctr, L, Lb);
  k_nms     <<<1, 1024, 0, stream>>>(L, deltas, anchors, out);
}

// Round 3
// 1166.181 us; speedup vs baseline: 2.0617x; 1.5806x over previous
//
#include <hip/hip_runtime.h>
#include <stdint.h>

#define AA 9
#define HH 384
#define WW 384
#define NN (AA*HH*WW)          // 1327104
#define PRE_NMS_ 6000
#define POST_NMS_ 300
#define NBUCK (1u<<20)
#define LB_CAP 4096
#define NPAD 6144               // 6000 padded to 96*64
#define NWORD 96                // NPAD/64

// ---------- helpers ----------

// Map float score -> uint32 key that is ASCENDING when score is DESCENDING.
static __device__ __forceinline__ uint32_t score_key(float s) {
  uint32_t b = __float_as_uint(s);
  uint32_t u = b ^ (((int32_t)b < 0) ? 0xFFFFFFFFu : 0x80000000u);
  return ~u;
}

// Sortable-ascending map for floats (used on y2 in the NMS key).
static __device__ __forceinline__ uint32_t f2s(float v) {
  uint32_t b = __float_as_uint(v);
  return b ^ (((int32_t)b < 0) ? 0xFFFFFFFFu : 0x80000000u);
}

// Exact replication of reference box decode + _clip_boxes + keep mask.
static __device__ __forceinline__ void compute_box(float4 an, float4 de,
    float& x1, float& y1, float& wc, float& hc, bool& keep) {
  float bx = fmaxf(an.x + de.x, 0.0f);
  float by = fmaxf(an.y + de.y, 0.0f);
  float bw = fmaxf(an.z + de.z, 0.0f);
  float bh = fmaxf(an.w + de.w, 0.0f);
  float x2 = bx + bw - 1.0f;
  float y2 = by + bh - 1.0f;
  x1 = fminf(bx, 383.0f);
  y1 = fminf(by, 383.0f);
  x2 = fminf(x2, 383.0f);
  y2 = fminf(y2, 383.0f);
  wc = x2 - x1 + 1.0f;
  hc = y2 - y1 + 1.0f;
  keep = (wc >= 2.0f) && (hc >= 2.0f);
}

// ---------- K1: histogram of descending score keys ----------
__global__ void k_hist(const float* __restrict__ scores,
                       const float4* __restrict__ deltas,
                       const float4* __restrict__ anchors,
                       uint32_t* __restrict__ hist) {
  int i = blockIdx.x * blockDim.x + threadIdx.x;
  if (i >= NN) return;
  float x1, y1, wc, hc; bool keep;
  compute_box(anchors[i], deltas[i], x1, y1, wc, hc, keep);
  uint32_t d = keep ? score_key(scores[i]) : 0xFF800000u;  // key(-inf)
  atomicAdd(&hist[d >> 12], 1u);
}

// ---------- K2a: group sums of the histogram ----------
__global__ __launch_bounds__(256) void k_psum(const uint32_t* __restrict__ hist,
                                              uint32_t* __restrict__ psum) {
  __shared__ uint32_t red[256];
  int b = blockIdx.x, t = threadIdx.x;
  const uint4* hv = (const uint4*)(hist + (size_t)b * 1024);
  uint4 v = hv[t];
  red[t] = v.x + v.y + v.z + v.w;
  __syncthreads();
  for (int off = 128; off; off >>= 1) {
    if (t < off) red[t] += red[t + off];
    __syncthreads();
  }
  if (t == 0) psum[b] = red[0];
}

// ---------- K2b: two-level shfl-scan -> threshold bucket B*, C0 ----------
// ctr[0]=lcnt ctr[1]=bcnt ctr[2]=B* ctr[3]=C0
__global__ __launch_bounds__(1024) void k_pick(const uint32_t* __restrict__ hist,
                                               const uint32_t* __restrict__ psum,
                                               uint32_t* __restrict__ ctr) {
  __shared__ uint32_t wsum[16], woff[16];
  __shared__ uint32_t gsel, cbase;
  int t = threadIdx.x, lane = t & 63, wv = t >> 6;

  // scan psum[1024]
  uint32_t v = psum[t];
  uint32_t pre = v;
  #pragma unroll
  for (int off = 1; off < 64; off <<= 1) {
    uint32_t u = __shfl_up(pre, off);
    if (lane >= off) pre += u;
  }
  if (lane == 63) wsum[wv] = pre;
  __syncthreads();
  if (t < 16) { uint32_t s = 0; for (int k = 0; k < t; ++k) s += wsum[k]; woff[t] = s; }
  __syncthreads();
  uint32_t incl = pre + woff[wv];
  uint32_t excl = incl - v;
  if (excl < PRE_NMS_ && incl >= PRE_NMS_) { gsel = t; cbase = excl; }
  __syncthreads();
  uint32_t g = gsel, cb = cbase;
  __syncthreads();   // protect wsum/woff reuse

  // scan the selected group's 1024 buckets
  v = hist[(size_t)g * 1024 + t];
  pre = v;
  #pragma unroll
  for (int off = 1; off < 64; off <<= 1) {
    uint32_t u = __shfl_up(pre, off);
    if (lane >= off) pre += u;
  }
  if (lane == 63) wsum[wv] = pre;
  __syncthreads();
  if (t < 16) { uint32_t s = 0; for (int k = 0; k < t; ++k) s += wsum[k]; woff[t] = s; }
  __syncthreads();
  incl = cb + pre + woff[wv];
  excl = incl - v;
  if (excl < PRE_NMS_ && incl >= PRE_NMS_) {
    ctr[2] = g * 1024 + t;   // B*
    ctr[3] = excl;           // C0
  }
}

// ---------- K3: gather candidates ----------
__global__ void k_gather(const float* __restrict__ scores,
                         const float4* __restrict__ deltas,
                         const float4* __restrict__ anchors,
                         uint32_t* __restrict__ ctr,
                         uint64_t* __restrict__ L,
                         uint64_t* __restrict__ Lb) {
  int i = blockIdx.x * blockDim.x + threadIdx.x;
  if (i >= NN) return;
  float x1, y1, wc, hc; bool keep;
  compute_box(anchors[i], deltas[i], x1, y1, wc, hc, keep);
  uint32_t d = keep ? score_key(scores[i]) : 0xFF800000u;
  uint32_t bk = d >> 12;
  uint32_t Bs = ctr[2];
  if (bk > Bs) return;
  uint64_t key = ((uint64_t)d << 32) | (uint32_t)i;
  if (bk < Bs) {
    uint32_t p = atomicAdd(&ctr[0], 1u);
    if (p < PRE_NMS_) L[p] = key;
  } else {
    uint32_t p = atomicAdd(&ctr[1], 1u);
    if (p < LB_CAP) Lb[p] = key;
  }
}

// ---------- K4: rank-select T smallest from boundary bucket -> L[C0..6000) ----------
__global__ __launch_bounds__(1024) void k_rankb(const uint32_t* __restrict__ ctr,
                                                const uint64_t* __restrict__ Lb,
                                                uint64_t* __restrict__ L) {
  __shared__ uint64_t sk[LB_CAP];
  int t = threadIdx.x;
  uint32_t Cb = ctr[1]; if (Cb > LB_CAP) Cb = LB_CAP;
  uint32_t C0 = ctr[3];
  uint32_t T = PRE_NMS_ - C0;
  for (uint32_t j = t; j < Cb; j += 1024) sk[j] = Lb[j];
  __syncthreads();
  for (uint32_t s = t; s < Cb; s += 1024) {
    uint64_t k = sk[s];
    uint32_t rnk = 0;
    for (uint32_t j = 0; j < Cb; ++j) rnk += (sk[j] < k) ? 1u : 0u;
    if (rnk < T) L[C0 + rnk] = k;
  }
}

// ---------- K5: per-candidate NMS key + box in OUTPUT format ----------
__global__ __launch_bounds__(256) void k_prep(const uint64_t* __restrict__ L,
                                              const float4* __restrict__ deltas,
                                              const float4* __restrict__ anchors,
                                              uint64_t* __restrict__ keyhi,
                                              uint32_t* __restrict__ keylo,
                                              float4* __restrict__ box4u) {
  int i = blockIdx.x * blockDim.x + threadIdx.x;
  if (i >= NPAD) return;
  bool real = false;
  uint32_t d = 0, idx = 0;
  if (i < PRE_NMS_) {
    uint64_t key = L[i];
    d = (uint32_t)(key >> 32); idx = (uint32_t)key;
    real = (idx < (uint32_t)NN);
  }
  if (real) {
    float x1, y1, wc, hc; bool keep;
    compute_box(anchors[idx], deltas[idx], x1, y1, wc, hc, keep);
    float y2 = y1 + hc - 1.0f;                 // exactly as reference _nms
    keyhi[i] = ((uint64_t)f2s(y2) << 32) | (uint32_t)(~d);
    keylo[i] = ~idx;
    box4u[i] = make_float4(x1, y1, wc, hc);
  } else {
    keyhi[i] = 0;
    keylo[i] = (uint32_t)(NPAD - i);           // unique sentinel tie-break
    box4u[i] = make_float4(0.f, 0.f, 0.f, 0.f);
  }
}

// ---------- K6: pairwise rank (descending key) via chunked counting ----------
__global__ __launch_bounds__(256) void k_rank(const uint64_t* __restrict__ keyhi,
                                              const uint32_t* __restrict__ keylo,
                                              uint32_t* __restrict__ rank) {
  __shared__ uint64_t shi[768];
  __shared__ uint32_t slo[768];
  int t = threadIdx.x;
  int ib = blockIdx.x >> 3;
  int c  = blockIdx.x & 7;
  int base = c * 768;
  for (int j = t; j < 768; j += 256) { shi[j] = keyhi[base + j]; slo[j] = keylo[base + j]; }
  __syncthreads();
  int i = ib * 256 + t;
  uint64_t hi = keyhi[i]; uint32_t lo = keylo[i];
  uint32_t cnt = 0;
  for (int j = 0; j < 768; ++j) {
    uint64_t hj = shi[j]; uint32_t lj = slo[j];
    cnt += ((hj > hi) || (hj == hi && lj > lo)) ? 1u : 0u;
  }
  atomicAdd(&rank[i], cnt);
}

// ---------- K7: scatter into sorted order + validity bits ----------
__global__ __launch_bounds__(256) void k_scatter(const uint64_t* __restrict__ keyhi,
                                                 const uint32_t* __restrict__ rank,
                                                 const float4* __restrict__ box4u,
                                                 float4* __restrict__ sbox4,
                                                 float* __restrict__ sarea,
                                                 float4* __restrict__ sobox,
                                                 unsigned long long* __restrict__ valid) {
  int i = blockIdx.x * blockDim.x + threadIdx.x;
  if (i >= NPAD) return;
  uint32_t r = rank[i];
  float4 b = box4u[i];
  float x2 = b.x + b.z - 1.0f;                 // exactly as reference _nms
  float y2 = b.y + b.w - 1.0f;
  sbox4[r] = make_float4(b.x, b.y, x2, y2);
  sarea[r] = b.z * b.w;
  sobox[r] = b;
  uint32_t d = ~(uint32_t)(keyhi[i] & 0xFFFFFFFFu);
  if (d < 0xFF800000u)                         // finite masked score only
    atomicOr(&valid[r >> 6], 1ull << (r & 63));
}

// ---------- K8: suppression matrix M[NPAD][NWORD] ----------
__global__ __launch_bounds__(512) void k_mat(const float4* __restrict__ sbox4,
                                             const float* __restrict__ sarea,
                                             uint64_t* __restrict__ M) {
  __shared__ float4 sb[NPAD];       // 98,304 B
  __shared__ float  sa[NPAD];       // 24,576 B
  int t = threadIdx.x;
  for (int j = t; j < NPAD; j += 512) { sb[j] = sbox4[j]; sa[j] = sarea[j]; }
  __syncthreads();
  int wid = t >> 6, l = t & 63;
  #pragma unroll
  for (int rr = 0; rr < 4; ++rr) {
    int r = blockIdx.x * 32 + wid * 4 + rr;
    float4 rb = sb[r];
    for (int w = 0; w < NWORD; ++w) {
      int j = w * 64 + l;
      float4 cb = sb[j];
      float ca = sa[j];
      float xx1 = fmaxf(cb.x, rb.x), yy1 = fmaxf(cb.y, rb.y);
      float xx2 = fminf(cb.z, rb.z), yy2 = fminf(cb.w, rb.w);
      float iw = fmaxf(xx2 - xx1 + 1.0f, 0.0f);
      float ih = fmaxf(yy2 - yy1 + 1.0f, 0.0f);
      float ratio = (iw * ih) / ca;            // IEEE divide, exact semantics
      unsigned long long m = __ballot(!(ratio < 0.7f));
      if (l == 0) M[(size_t)r * NWORD + w] = m;
    }
  }
}

// ---------- K9: single-wave barrier-free sequential NMS ----------
__global__ __launch_bounds__(64) void k_seq(const unsigned long long* __restrict__ valid,
                                            const uint64_t* __restrict__ M,
                                            const float4* __restrict__ sobox,
                                            float* __restrict__ out) {
  int l = threadIdx.x;
  unsigned long long v0 = valid[l];
  unsigned long long v1 = (l < 32) ? valid[64 + l] : 0ull;
  int cnt = 0;
  for (; cnt < POST_NMS_; ++cnt) {
    unsigned long long b0 = __ballot(v0 != 0ull);
    unsigned long long b1 = __ballot(v1 != 0ull);
    if ((b0 | b1) == 0ull) break;
    int w = b0 ? (__ffsll(b0) - 1) : (64 + __ffsll(b1) - 1);
    unsigned long long vw = __shfl((w < 64) ? v0 : v1, w & 63);
    int bit = __ffsll(vw) - 1;
    int win = w * 64 + bit;
    if (l == 0) {
      float4 ob = sobox[win];
      *(float4*)(out + cnt * 4) = ob;
    }
    const uint64_t* Mr = M + (size_t)win * NWORD;
    unsigned long long m0 = Mr[l];
    unsigned long long m1 = (l < 32) ? Mr[64 + l] : 0ull;
    v0 &= ~m0; v1 &= ~m1;
  }
  for (int j = l; j < (POST_NMS_ - cnt) * 4; j += 64) out[cnt * 4 + j] = 0.0f;
}

// ---------- launch ----------
extern "C" void kernel_launch(void* const* d_in, const int* in_sizes, int n_in,
                              void* d_out, int out_size, void* d_ws, size_t ws_size,
                              hipStream_t stream) {
  const float*  scores  = (const float*)d_in[0];
  const float4* deltas  = (const float4*)d_in[1];
  const float4* anchors = (const float4*)d_in[2];
  float* out = (float*)d_out;

  // ws layout; M (4,718,592 B) overlays hist (4 MiB, dead after k_pick)
  uint8_t* w8 = (uint8_t*)d_ws;
  const size_t A0 = (size_t)NPAD * NWORD * 8;            // 4,718,592
  uint32_t* hist = (uint32_t*)w8;
  uint64_t* M    = (uint64_t*)w8;
  uint32_t* ctr  = (uint32_t*)(w8 + A0);                 //    64 B
  unsigned long long* valid = (unsigned long long*)(w8 + A0 + 64);   // 1024 B
  uint32_t* psum = (uint32_t*)(w8 + A0 + 1088);          //  4096 B
  uint32_t* rank = (uint32_t*)(w8 + A0 + 5184);          // 24576 B
  uint64_t* L    = (uint64_t*)(w8 + A0 + 29760);         // 48000 B
  uint64_t* Lb   = (uint64_t*)(w8 + A0 + 77760);         // 32768 B
  uint64_t* keyhi= (uint64_t*)(w8 + A0 + 110528);        // 49152 B
  uint32_t* keylo= (uint32_t*)(w8 + A0 + 159680);        // 24576 B
  float4*   box4u= (float4*)  (w8 + A0 + 184256);        // 98304 B
  float4*   sbox4= (float4*)  (w8 + A0 + 282560);        // 98304 B
  float*    sarea= (float*)   (w8 + A0 + 380864);        // 24576 B
  float4*   sobox= (float4*)  (w8 + A0 + 405440);        // 98304 B
  // total: A0 + 503,744 = 5,222,336 B

  hipMemsetAsync(hist, 0, (size_t)NBUCK * 4, stream);
  hipMemsetAsync(w8 + A0, 0, 29760, stream);             // ctr+valid+psum+rank

  int blocks = NN / 256;                                  // 5184 exact
  k_hist   <<<blocks, 256, 0, stream>>>(scores, deltas, anchors, hist);
  k_psum   <<<1024, 256, 0, stream>>>(hist, psum);
  k_pick   <<<1, 1024, 0, stream>>>(hist, psum, ctr);
  k_gather <<<blocks, 256, 0, stream>>>(scores, deltas, anchors, ctr, L, Lb);
  k_rankb  <<<1, 1024, 0, stream>>>(ctr, Lb, L);
  k_prep   <<<NPAD / 256, 256, 0, stream>>>(L, deltas, anchors, keyhi, keylo, box4u);
  k_rank   <<<192, 256, 0, stream>>>(keyhi, keylo, rank);
  k_scatter<<<NPAD / 256, 256, 0, stream>>>(keyhi, rank, box4u, sbox4, sarea, sobox, valid);
  k_mat    <<<192, 512, 0, stream>>>(sbox4, sarea, M);
  k_seq    <<<1, 64, 0, stream>>>(valid, M, sobox, out);
}

// Round 5
// 425.723 us; speedup vs baseline: 5.6475x; 2.7393x over previous
//
#include <hip/hip_runtime.h>
#include <stdint.h>

#define NN 1327104              // 9*384*384
#define NQ 331776               // NN/4
#define NB 1296                 // blocks for full-array passes (NB*256*4 == NN)
#define PRE_NMS_ 6000
#define POST_NMS_ 300
#define LB_CAP 4096
#define NPAD 6144               // 6000 padded to 96*64
#define NWORD 96                // NPAD/64

// ---------- helpers ----------

// Map float score -> uint32 key that is ASCENDING when score is DESCENDING.
static __device__ __forceinline__ uint32_t score_key(float s) {
  uint32_t b = __float_as_uint(s);
  uint32_t u = b ^ (((int32_t)b < 0) ? 0xFFFFFFFFu : 0x80000000u);
  return ~u;
}

// Sortable-ascending map for floats (used on y2 in the NMS key).
static __device__ __forceinline__ uint32_t f2s(float v) {
  uint32_t b = __float_as_uint(v);
  return b ^ (((int32_t)b < 0) ? 0xFFFFFFFFu : 0x80000000u);
}

// Exact replication of reference box decode + _clip_boxes + keep mask.
static __device__ __forceinline__ void compute_box(float4 an, float4 de,
    float& x1, float& y1, float& wc, float& hc, bool& keep) {
  float bx = fmaxf(an.x + de.x, 0.0f);
  float by = fmaxf(an.y + de.y, 0.0f);
  float bw = fmaxf(an.z + de.z, 0.0f);
  float bh = fmaxf(an.w + de.w, 0.0f);
  float x2 = bx + bw - 1.0f;
  float y2 = by + bh - 1.0f;
  x1 = fminf(bx, 383.0f);
  y1 = fminf(by, 383.0f);
  x2 = fminf(x2, 383.0f);
  y2 = fminf(y2, 383.0f);
  wc = x2 - x1 + 1.0f;
  hc = y2 - y1 + 1.0f;
  keep = (wc >= 2.0f) && (hc >= 2.0f);
}

// ---------- Pass A: decode once, write d[], LDS hist of d>>24, flush to hist[256] ----------
__global__ __launch_bounds__(256) void k_hA(const float* __restrict__ scores,
                                            const float4* __restrict__ deltas,
                                            const float4* __restrict__ anchors,
                                            uint32_t* __restrict__ darr,
                                            uint32_t* __restrict__ hist) {
  __shared__ uint32_t lh[256];
  int t = threadIdx.x;
  lh[t] = 0;
  __syncthreads();
  int base = blockIdx.x * 256 + t;
  #pragma unroll
  for (int it = 0; it < 4; ++it) {
    int i = base + it * NQ;
    float x1, y1, wc, hc; bool keep;
    compute_box(anchors[i], deltas[i], x1, y1, wc, hc, keep);
    uint32_t d = keep ? score_key(scores[i]) : 0xFF800000u;   // key(-inf)
    darr[i] = d;
    atomicAdd(&lh[d >> 24], 1u);
  }
  __syncthreads();
  uint32_t c = lh[t];
  if (c) atomicAdd(&hist[t], c);     // 256 hot lines in L2, no scatter
}

// ---------- Passes B/C: refine 8 bits, reading only d[] ----------
__global__ __launch_bounds__(256) void k_hBC(const uint4* __restrict__ dv,
                                             const uint32_t* __restrict__ ctr,
                                             uint32_t* __restrict__ hist,
                                             int level) {
  __shared__ uint32_t lh[256];
  int t = threadIdx.x;
  lh[t] = 0;
  __syncthreads();
  uint32_t match, shift;
  if (level == 2) { match = ctr[4]; shift = 24; }
  else            { match = (ctr[4] << 8) | ctr[5]; shift = 16; }
  uint4 v = dv[blockIdx.x * 256 + t];
  uint32_t arr[4] = {v.x, v.y, v.z, v.w};
  #pragma unroll
  for (int k = 0; k < 4; ++k) {
    uint32_t d = arr[k];
    if ((d >> shift) == match) atomicAdd(&lh[(d >> (shift - 8)) & 255u], 1u);
  }
  __syncthreads();
  uint32_t c = lh[t];
  if (c) atomicAdd(&hist[t], c);
}

// ---------- pick crossing bucket among hist[256]; zero hist for next pass ----------
// ctr[3] = running count strictly above selected prefix; ctr[slot] = selected byte
__global__ __launch_bounds__(64) void k_pick8(uint32_t* __restrict__ hist,
                                              uint32_t* __restrict__ ctr, int slot) {
  int l = threadIdx.x;
  uint32_t base = ctr[3];
  uint32_t h0 = hist[l*4], h1 = hist[l*4+1], h2 = hist[l*4+2], h3 = hist[l*4+3];
  hist[l*4] = 0; hist[l*4+1] = 0; hist[l*4+2] = 0; hist[l*4+3] = 0;  // reset for next pass
  uint32_t c0 = h0, c1 = c0 + h1, c2 = c1 + h2, c3 = c2 + h3;
  uint32_t p = c3;
  #pragma unroll
  for (int off = 1; off < 64; off <<= 1) {
    uint32_t u = __shfl_up(p, off);
    if (l >= off) p += u;
  }
  uint32_t excl = p - c3;
  bool hit = (base + p >= PRE_NMS_) && (base + excl < PRE_NMS_);
  if (hit) {                                // exactly one lane (p monotone)
    uint32_t k, cb;
    if      (base + excl + c0 >= PRE_NMS_) { k = 0; cb = 0;  }
    else if (base + excl + c1 >= PRE_NMS_) { k = 1; cb = c0; }
    else if (base + excl + c2 >= PRE_NMS_) { k = 2; cb = c1; }
    else                                   { k = 3; cb = c2; }
    ctr[slot] = (uint32_t)(l * 4) + k;
    ctr[3] = base + excl + cb;
  }
}

// ---------- gather candidates by 24-bit prefix ----------
__global__ __launch_bounds__(256) void k_gather(const uint4* __restrict__ dv,
                                                uint32_t* __restrict__ ctr,
                                                uint64_t* __restrict__ L,
                                                uint64_t* __restrict__ Lb) {
  int g = blockIdx.x * 256 + threadIdx.x;
  uint4 v = dv[g];
  uint32_t P24 = (ctr[4] << 16) | (ctr[5] << 8) | ctr[6];
  uint32_t arr[4] = {v.x, v.y, v.z, v.w};
  #pragma unroll
  for (int k = 0; k < 4; ++k) {
    uint32_t d = arr[k];
    uint32_t p24 = d >> 8;
    uint32_t idx = (uint32_t)(g * 4 + k);
    if (p24 < P24) {
      uint32_t p = atomicAdd(&ctr[0], 1u);
      if (p < PRE_NMS_) L[p] = ((uint64_t)d << 32) | idx;
    } else if (p24 == P24) {
      uint32_t p = atomicAdd(&ctr[1], 1u);
      if (p < LB_CAP) Lb[p] = ((uint64_t)d << 32) | idx;
    }
  }
}

// ---------- rank-select T smallest from boundary bucket -> L[C0..6000) ----------
__global__ __launch_bounds__(256) void k_rankb(const uint32_t* __restrict__ ctr,
                                               const uint64_t* __restrict__ Lb,
                                               uint64_t* __restrict__ L) {
  __shared__ uint64_t sk[LB_CAP];
  int t = threadIdx.x;
  uint32_t Cb = ctr[1]; if (Cb > LB_CAP) Cb = LB_CAP;
  uint32_t C0 = ctr[3];
  uint32_t T = PRE_NMS_ - C0;
  for (uint32_t j = t; j < Cb; j += 256) sk[j] = Lb[j];
  __syncthreads();
  for (uint32_t s = t; s < Cb; s += 256) {
    uint64_t k = sk[s];
    uint32_t r = 0;
    for (uint32_t j = 0; j < Cb; ++j) r += (sk[j] < k) ? 1u : 0u;
    if (r < T) L[C0 + r] = k;
  }
}

// ---------- per-candidate NMS key + box in output format ----------
__global__ __launch_bounds__(256) void k_prep(const uint64_t* __restrict__ L,
                                              const float4* __restrict__ deltas,
                                              const float4* __restrict__ anchors,
                                              uint64_t* __restrict__ keyhi,
                                              uint32_t* __restrict__ keylo,
                                              float4* __restrict__ box4u) {
  int i = blockIdx.x * blockDim.x + threadIdx.x;
  if (i >= NPAD) return;
  if (i < PRE_NMS_) {
    uint64_t key = L[i];
    uint32_t d = (uint32_t)(key >> 32), idx = (uint32_t)key;
    float x1, y1, wc, hc; bool keep;
    compute_box(anchors[idx], deltas[idx], x1, y1, wc, hc, keep);
    float y2 = y1 + hc - 1.0f;                 // exactly as reference _nms
    keyhi[i] = ((uint64_t)f2s(y2) << 32) | (uint32_t)(~d);
    keylo[i] = ~idx;
    box4u[i] = make_float4(x1, y1, wc, hc);
  } else {
    keyhi[i] = 0;
    keylo[i] = (uint32_t)(NPAD - i);           // unique sentinel tie-break
    box4u[i] = make_float4(0.f, 0.f, 0.f, 0.f);
  }
}

// ---------- pairwise rank, chunked; plain stores to rank2d[i][8] ----------
__global__ __launch_bounds__(256) void k_rank(const uint64_t* __restrict__ keyhi,
                                              const uint32_t* __restrict__ keylo,
                                              uint32_t* __restrict__ rank2d) {
  __shared__ uint64_t shi[768];
  __shared__ uint32_t slo[768];
  int t = threadIdx.x;
  int ib = blockIdx.x >> 3;
  int c  = blockIdx.x & 7;
  int base = c * 768;
  for (int j = t; j < 768; j += 256) { shi[j] = keyhi[base + j]; slo[j] = keylo[base + j]; }
  __syncthreads();
  int i = ib * 256 + t;
  uint64_t hi = keyhi[i]; uint32_t lo = keylo[i];
  uint32_t cnt = 0;
  for (int j = 0; j < 768; ++j) {
    uint64_t hj = shi[j]; uint32_t lj = slo[j];
    cnt += ((hj > hi) || (hj == hi && lj > lo)) ? 1u : 0u;
  }
  rank2d[i * 8 + c] = cnt;
}

// ---------- scatter into sorted order + validity bits ----------
__global__ __launch_bounds__(256) void k_scatter(const uint64_t* __restrict__ keyhi,
                                                 const uint32_t* __restrict__ rank2d,
                                                 const float4* __restrict__ box4u,
                                                 float4* __restrict__ sbox4,
                                                 float* __restrict__ sarea,
                                                 float4* __restrict__ sobox,
                                                 unsigned long long* __restrict__ valid) {
  int i = blockIdx.x * blockDim.x + threadIdx.x;
  if (i >= NPAD) return;
  const uint4* rp = (const uint4*)(rank2d + (size_t)i * 8);
  uint4 a = rp[0], b4 = rp[1];
  uint32_t r = a.x + a.y + a.z + a.w + b4.x + b4.y + b4.z + b4.w;
  float4 b = box4u[i];
  float x2 = b.x + b.z - 1.0f;                 // exactly as reference _nms
  float y2 = b.y + b.w - 1.0f;
  sbox4[r] = make_float4(b.x, b.y, x2, y2);
  sarea[r] = b.z * b.w;
  sobox[r] = b;
  uint32_t d = ~(uint32_t)(keyhi[i] & 0xFFFFFFFFu);
  if (d < 0xFF800000u)                         // finite masked score only
    atomicOr(&valid[r >> 6], 1ull << (r & 63));
}

// ---------- suppression matrix M[NPAD][NWORD] ----------
__global__ __launch_bounds__(512) void k_mat(const float4* __restrict__ sbox4,
                                             const float* __restrict__ sarea,
                                             uint64_t* __restrict__ M) {
  __shared__ float4 sb[NPAD];       // 98,304 B
  __shared__ float  sa[NPAD];       // 24,576 B
  int t = threadIdx.x;
  for (int j = t; j < NPAD; j += 512) { sb[j] = sbox4[j]; sa[j] = sarea[j]; }
  __syncthreads();
  int wid = t >> 6, l = t & 63;
  #pragma unroll
  for (int rr = 0; rr < 4; ++rr) {
    int r = blockIdx.x * 32 + wid * 4 + rr;
    float4 rb = sb[r];
    for (int w = 0; w < NWORD; ++w) {
      int j = w * 64 + l;
      float4 cb = sb[j];
      float ca = sa[j];
      float xx1 = fmaxf(cb.x, rb.x), yy1 = fmaxf(cb.y, rb.y);
      float xx2 = fminf(cb.z, rb.z), yy2 = fminf(cb.w, rb.w);
      float iw = fmaxf(xx2 - xx1 + 1.0f, 0.0f);
      float ih = fmaxf(yy2 - yy1 + 1.0f, 0.0f);
      float ratio = (iw * ih) / ca;            // IEEE divide, exact semantics
      unsigned long long m = __ballot(!(ratio < 0.7f));
      if (l == 0) M[(size_t)r * NWORD + w] = m;
    }
  }
}

// ---------- single-wave barrier-free sequential NMS ----------
__global__ __launch_bounds__(64) void k_seq(const unsigned long long* __restrict__ valid,
                                            const uint64_t* __restrict__ M,
                                            const float4* __restrict__ sobox,
                                            float* __restrict__ out) {
  int l = threadIdx.x;
  unsigned long long v0 = valid[l];
  unsigned long long v1 = (l < 32) ? valid[64 + l] : 0ull;
  int cnt = 0;
  for (; cnt < POST_NMS_; ++cnt) {
    unsigned long long b0 = __ballot(v0 != 0ull);
    unsigned long long b1 = __ballot(v1 != 0ull);
    if ((b0 | b1) == 0ull) break;
    int w = b0 ? (__ffsll(b0) - 1) : (64 + __ffsll(b1) - 1);
    unsigned long long vw = __shfl((w < 64) ? v0 : v1, w & 63);
    int bit = __ffsll(vw) - 1;
    int win = w * 64 + bit;
    if (l == 0) {
      float4 ob = sobox[win];
      *(float4*)(out + cnt * 4) = ob;
    }
    const uint64_t* Mr = M + (size_t)win * NWORD;
    unsigned long long m0 = Mr[l];
    unsigned long long m1 = (l < 32) ? Mr[64 + l] : 0ull;
    v0 &= ~m0; v1 &= ~m1;
  }
  for (int j = l; j < (POST_NMS_ - cnt) * 4; j += 64) out[cnt * 4 + j] = 0.0f;
}

// ---------- launch ----------
extern "C" void kernel_launch(void* const* d_in, const int* in_sizes, int n_in,
                              void* d_out, int out_size, void* d_ws, size_t ws_size,
                              hipStream_t stream) {
  const float*  scores  = (const float*)d_in[0];
  const float4* deltas  = (const float4*)d_in[1];
  const float4* anchors = (const float4*)d_in[2];
  float* out = (float*)d_out;

  uint8_t* w8 = (uint8_t*)d_ws;
  // region 0: d[] (5,308,416 B), live from k_hA until k_gather; then overlaid by:
  //   M @0 (4,718,592), sbox4/sarea/sobox/valid in the tail
  uint32_t* darr  = (uint32_t*)w8;
  uint64_t* M     = (uint64_t*)w8;
  float4*   sbox4 = (float4*)(w8 + 4718592);               //  98,304
  float*    sarea = (float*) (w8 + 4816896);               //  24,576
  float4*   sobox = (float4*)(w8 + 4841472);               //  98,304
  unsigned long long* valid = (unsigned long long*)(w8 + 4939776); // 1,024 -> 4,940,800 < 5,308,416
  // region 1 (fresh, no overlay with darr): @5,308,416
  uint64_t* keyhi  = (uint64_t*)(w8 + 5308416);            //  49,152
  uint32_t* keylo  = (uint32_t*)(w8 + 5357568);            //  24,576
  float4*   box4u  = (float4*)  (w8 + 5382144);            //  98,304
  uint32_t* rank2d = (uint32_t*)(w8 + 5480448);            // 196,608 -> 5,677,056
  // region 2: persistent small
  uint32_t* hist = (uint32_t*)(w8 + 5677056);              //   1,024
  uint32_t* ctr  = (uint32_t*)(w8 + 5678080);              //      64
  uint64_t* L    = (uint64_t*)(w8 + 5678144);              //  48,000
  uint64_t* Lb   = (uint64_t*)(w8 + 5726144);              //  32,768 -> 5,758,912 total

  const uint4* dv = (const uint4*)darr;

  hipMemsetAsync(hist, 0, 1088, stream);     // hist[256] + ctr (contiguous)

  k_hA   <<<NB, 256, 0, stream>>>(scores, deltas, anchors, darr, hist);
  k_pick8<<<1, 64, 0, stream>>>(hist, ctr, 4);
  k_hBC  <<<NB, 256, 0, stream>>>(dv, ctr, hist, 2);
  k_pick8<<<1, 64, 0, stream>>>(hist, ctr, 5);
  k_hBC  <<<NB, 256, 0, stream>>>(dv, ctr, hist, 3);
  k_pick8<<<1, 64, 0, stream>>>(hist, ctr, 6);
  k_gather <<<NB, 256, 0, stream>>>(dv, ctr, L, Lb);
  // darr is dead from here on — NOW it is safe to clear `valid` (overlays darr tail)
  hipMemsetAsync(valid, 0, 1024, stream);
  k_rankb  <<<1, 256, 0, stream>>>(ctr, Lb, L);
  k_prep   <<<NPAD / 256, 256, 0, stream>>>(L, deltas, anchors, keyhi, keylo, box4u);
  k_rank   <<<192, 256, 0, stream>>>(keyhi, keylo, rank2d);
  k_scatter<<<NPAD / 256, 256, 0, stream>>>(keyhi, rank2d, box4u, sbox4, sarea, sobox, valid);
  k_mat    <<<192, 512, 0, stream>>>(sbox4, sarea, M);
  k_seq    <<<1, 64, 0, stream>>>(valid, M, sobox, out);
}

// Round 6
// 350.923 us; speedup vs baseline: 6.8513x; 1.2132x over previous
//
#include <hip/hip_runtime.h>
#include <stdint.h>

#define NN 1327104              // 9*384*384
#define NQ 331776               // NN/4
#define NB 1296                 // blocks for full-array passes (NB*256*4 == NN)
#define PRE_NMS_ 6000
#define POST_NMS_ 300
#define LB_CAP 4096
#define NPAD 6144               // 6000 padded to 96*64
#define NWORD 96                // NPAD/64
#define KB 16                   // batch size for k_seq rounds

// ---------- helpers ----------

// Map float score -> uint32 key that is ASCENDING when score is DESCENDING.
static __device__ __forceinline__ uint32_t score_key(float s) {
  uint32_t b = __float_as_uint(s);
  uint32_t u = b ^ (((int32_t)b < 0) ? 0xFFFFFFFFu : 0x80000000u);
  return ~u;
}

// Sortable-ascending map for floats (used on y2 in the NMS key).
static __device__ __forceinline__ uint32_t f2s(float v) {
  uint32_t b = __float_as_uint(v);
  return b ^ (((int32_t)b < 0) ? 0xFFFFFFFFu : 0x80000000u);
}

// Exact replication of reference box decode + _clip_boxes + keep mask.
static __device__ __forceinline__ void compute_box(float4 an, float4 de,
    float& x1, float& y1, float& wc, float& hc, bool& keep) {
  float bx = fmaxf(an.x + de.x, 0.0f);
  float by = fmaxf(an.y + de.y, 0.0f);
  float bw = fmaxf(an.z + de.z, 0.0f);
  float bh = fmaxf(an.w + de.w, 0.0f);
  float x2 = bx + bw - 1.0f;
  float y2 = by + bh - 1.0f;
  x1 = fminf(bx, 383.0f);
  y1 = fminf(by, 383.0f);
  x2 = fminf(x2, 383.0f);
  y2 = fminf(y2, 383.0f);
  wc = x2 - x1 + 1.0f;
  hc = y2 - y1 + 1.0f;
  keep = (wc >= 2.0f) && (hc >= 2.0f);
}

// ---------- Pass A: decode once, write d[], LDS hist of d>>24, flush to hist[256] ----------
__global__ __launch_bounds__(256) void k_hA(const float* __restrict__ scores,
                                            const float4* __restrict__ deltas,
                                            const float4* __restrict__ anchors,
                                            uint32_t* __restrict__ darr,
                                            uint32_t* __restrict__ hist) {
  __shared__ uint32_t lh[256];
  int t = threadIdx.x;
  lh[t] = 0;
  __syncthreads();
  int base = blockIdx.x * 256 + t;
  #pragma unroll
  for (int it = 0; it < 4; ++it) {
    int i = base + it * NQ;
    float x1, y1, wc, hc; bool keep;
    compute_box(anchors[i], deltas[i], x1, y1, wc, hc, keep);
    uint32_t d = keep ? score_key(scores[i]) : 0xFF800000u;   // key(-inf)
    darr[i] = d;
    atomicAdd(&lh[d >> 24], 1u);
  }
  __syncthreads();
  uint32_t c = lh[t];
  if (c) atomicAdd(&hist[t], c);     // 256 hot lines in L2, no scatter
}

// ---------- Passes B/C: refine 8 bits, reading only d[] ----------
__global__ __launch_bounds__(256) void k_hBC(const uint4* __restrict__ dv,
                                             const uint32_t* __restrict__ ctr,
                                             uint32_t* __restrict__ hist,
                                             int level) {
  __shared__ uint32_t lh[256];
  int t = threadIdx.x;
  lh[t] = 0;
  __syncthreads();
  uint32_t match, shift;
  if (level == 2) { match = ctr[4]; shift = 24; }
  else            { match = (ctr[4] << 8) | ctr[5]; shift = 16; }
  uint4 v = dv[blockIdx.x * 256 + t];
  uint32_t arr[4] = {v.x, v.y, v.z, v.w};
  #pragma unroll
  for (int k = 0; k < 4; ++k) {
    uint32_t d = arr[k];
    if ((d >> shift) == match) atomicAdd(&lh[(d >> (shift - 8)) & 255u], 1u);
  }
  __syncthreads();
  uint32_t c = lh[t];
  if (c) atomicAdd(&hist[t], c);
}

// ---------- pick crossing bucket among hist[256]; zero hist for next pass ----------
__global__ __launch_bounds__(64) void k_pick8(uint32_t* __restrict__ hist,
                                              uint32_t* __restrict__ ctr, int slot) {
  int l = threadIdx.x;
  uint32_t base = ctr[3];
  uint32_t h0 = hist[l*4], h1 = hist[l*4+1], h2 = hist[l*4+2], h3 = hist[l*4+3];
  hist[l*4] = 0; hist[l*4+1] = 0; hist[l*4+2] = 0; hist[l*4+3] = 0;
  uint32_t c0 = h0, c1 = c0 + h1, c2 = c1 + h2, c3 = c2 + h3;
  uint32_t p = c3;
  #pragma unroll
  for (int off = 1; off < 64; off <<= 1) {
    uint32_t u = __shfl_up(p, off);
    if (l >= off) p += u;
  }
  uint32_t excl = p - c3;
  bool hit = (base + p >= PRE_NMS_) && (base + excl < PRE_NMS_);
  if (hit) {
    uint32_t k, cb;
    if      (base + excl + c0 >= PRE_NMS_) { k = 0; cb = 0;  }
    else if (base + excl + c1 >= PRE_NMS_) { k = 1; cb = c0; }
    else if (base + excl + c2 >= PRE_NMS_) { k = 2; cb = c1; }
    else                                   { k = 3; cb = c2; }
    ctr[slot] = (uint32_t)(l * 4) + k;
    ctr[3] = base + excl + cb;
  }
}

// ---------- gather candidates by 24-bit prefix ----------
__global__ __launch_bounds__(256) void k_gather(const uint4* __restrict__ dv,
                                                uint32_t* __restrict__ ctr,
                                                uint64_t* __restrict__ L,
                                                uint64_t* __restrict__ Lb) {
  int g = blockIdx.x * 256 + threadIdx.x;
  uint4 v = dv[g];
  uint32_t P24 = (ctr[4] << 16) | (ctr[5] << 8) | ctr[6];
  uint32_t arr[4] = {v.x, v.y, v.z, v.w};
  #pragma unroll
  for (int k = 0; k < 4; ++k) {
    uint32_t d = arr[k];
    uint32_t p24 = d >> 8;
    uint32_t idx = (uint32_t)(g * 4 + k);
    if (p24 < P24) {
      uint32_t p = atomicAdd(&ctr[0], 1u);
      if (p < PRE_NMS_) L[p] = ((uint64_t)d << 32) | idx;
    } else if (p24 == P24) {
      uint32_t p = atomicAdd(&ctr[1], 1u);
      if (p < LB_CAP) Lb[p] = ((uint64_t)d << 32) | idx;
    }
  }
}

// ---------- rank-select T smallest from boundary bucket -> L[C0..6000) ----------
__global__ __launch_bounds__(256) void k_rankb(const uint32_t* __restrict__ ctr,
                                               const uint64_t* __restrict__ Lb,
                                               uint64_t* __restrict__ L) {
  __shared__ uint64_t sk[LB_CAP];
  int t = threadIdx.x;
  uint32_t Cb = ctr[1]; if (Cb > LB_CAP) Cb = LB_CAP;
  uint32_t C0 = ctr[3];
  uint32_t T = PRE_NMS_ - C0;
  for (uint32_t j = t; j < Cb; j += 256) sk[j] = Lb[j];
  __syncthreads();
  for (uint32_t s = t; s < Cb; s += 256) {
    uint64_t k = sk[s];
    uint32_t r = 0;
    for (uint32_t j = 0; j < Cb; ++j) r += (sk[j] < k) ? 1u : 0u;
    if (r < T) L[C0 + r] = k;
  }
}

// ---------- per-candidate NMS key + box in output format ----------
__global__ __launch_bounds__(256) void k_prep(const uint64_t* __restrict__ L,
                                              const float4* __restrict__ deltas,
                                              const float4* __restrict__ anchors,
                                              uint64_t* __restrict__ keyhi,
                                              uint32_t* __restrict__ keylo,
                                              float4* __restrict__ box4u) {
  int i = blockIdx.x * blockDim.x + threadIdx.x;
  if (i >= NPAD) return;
  if (i < PRE_NMS_) {
    uint64_t key = L[i];
    uint32_t d = (uint32_t)(key >> 32), idx = (uint32_t)key;
    float x1, y1, wc, hc; bool keep;
    compute_box(anchors[idx], deltas[idx], x1, y1, wc, hc, keep);
    float y2 = y1 + hc - 1.0f;                 // exactly as reference _nms
    keyhi[i] = ((uint64_t)f2s(y2) << 32) | (uint32_t)(~d);
    keylo[i] = ~idx;
    box4u[i] = make_float4(x1, y1, wc, hc);
  } else {
    keyhi[i] = 0;
    keylo[i] = (uint32_t)(NPAD - i);           // unique sentinel tie-break
    box4u[i] = make_float4(0.f, 0.f, 0.f, 0.f);
  }
}

// ---------- pairwise rank, chunked; plain stores to rank2d[i][8] ----------
__global__ __launch_bounds__(256) void k_rank(const uint64_t* __restrict__ keyhi,
                                              const uint32_t* __restrict__ keylo,
                                              uint32_t* __restrict__ rank2d) {
  __shared__ uint64_t shi[768];
  __shared__ uint32_t slo[768];
  int t = threadIdx.x;
  int ib = blockIdx.x >> 3;
  int c  = blockIdx.x & 7;
  int base = c * 768;
  for (int j = t; j < 768; j += 256) { shi[j] = keyhi[base + j]; slo[j] = keylo[base + j]; }
  __syncthreads();
  int i = ib * 256 + t;
  uint64_t hi = keyhi[i]; uint32_t lo = keylo[i];
  uint32_t cnt = 0;
  for (int j = 0; j < 768; ++j) {
    uint64_t hj = shi[j]; uint32_t lj = slo[j];
    cnt += ((hj > hi) || (hj == hi && lj > lo)) ? 1u : 0u;
  }
  rank2d[i * 8 + c] = cnt;
}

// ---------- scatter into sorted order + validity bits ----------
__global__ __launch_bounds__(256) void k_scatter(const uint64_t* __restrict__ keyhi,
                                                 const uint32_t* __restrict__ rank2d,
                                                 const float4* __restrict__ box4u,
                                                 float4* __restrict__ sbox4,
                                                 float* __restrict__ sarea,
                                                 float4* __restrict__ sobox,
                                                 unsigned long long* __restrict__ valid) {
  int i = blockIdx.x * blockDim.x + threadIdx.x;
  if (i >= NPAD) return;
  const uint4* rp = (const uint4*)(rank2d + (size_t)i * 8);
  uint4 a = rp[0], b4 = rp[1];
  uint32_t r = a.x + a.y + a.z + a.w + b4.x + b4.y + b4.z + b4.w;
  float4 b = box4u[i];
  float x2 = b.x + b.z - 1.0f;                 // exactly as reference _nms
  float y2 = b.y + b.w - 1.0f;
  sbox4[r] = make_float4(b.x, b.y, x2, y2);
  sarea[r] = b.z * b.w;
  sobox[r] = b;
  uint32_t d = ~(uint32_t)(keyhi[i] & 0xFFFFFFFFu);
  if (d < 0xFF800000u)                         // finite masked score only
    atomicOr(&valid[r >> 6], 1ull << (r & 63));
}

// ---------- suppression matrix M[NPAD][NWORD] ----------
__global__ __launch_bounds__(512) void k_mat(const float4* __restrict__ sbox4,
                                             const float* __restrict__ sarea,
                                             uint64_t* __restrict__ M) {
  __shared__ float4 sb[NPAD];       // 98,304 B
  __shared__ float  sa[NPAD];       // 24,576 B
  int t = threadIdx.x;
  for (int j = t; j < NPAD; j += 512) { sb[j] = sbox4[j]; sa[j] = sarea[j]; }
  __syncthreads();
  int wid = t >> 6, l = t & 63;
  #pragma unroll
  for (int rr = 0; rr < 4; ++rr) {
    int r = blockIdx.x * 32 + wid * 4 + rr;
    float4 rb = sb[r];
    for (int w = 0; w < NWORD; ++w) {
      int j = w * 64 + l;
      float4 cb = sb[j];
      float ca = sa[j];
      float xx1 = fmaxf(cb.x, rb.x), yy1 = fmaxf(cb.y, rb.y);
      float xx2 = fminf(cb.z, rb.z), yy2 = fminf(cb.w, rb.w);
      float iw = fmaxf(xx2 - xx1 + 1.0f, 0.0f);
      float ih = fmaxf(yy2 - yy1 + 1.0f, 0.0f);
      float ratio = (iw * ih) / ca;            // IEEE divide, exact semantics
      unsigned long long m = __ballot(!(ratio < 0.7f));
      if (l == 0) M[(size_t)r * NWORD + w] = m;
    }
  }
}

// ---------- single-wave batched-greedy NMS: 16 row loads per latency round ----------
#define FOR16(F) F(0) F(1) F(2) F(3) F(4) F(5) F(6) F(7) \
                 F(8) F(9) F(10) F(11) F(12) F(13) F(14) F(15)

__global__ __launch_bounds__(64) void k_seq(const unsigned long long* __restrict__ valid,
                                            const uint64_t* __restrict__ M,
                                            const float4* __restrict__ sobox,
                                            float* __restrict__ out) {
  __shared__ int cslot[KB];
  int l = threadIdx.x;
  unsigned long long v0 = valid[l];
  unsigned long long v1 = (l < 32) ? valid[64 + l] : 0ull;
  uint32_t cnt = 0;

  for (;;) {
    // ---- count + prefix-rank valid candidates in word order ----
    uint32_t n0 = (uint32_t)__popcll(v0);
    uint32_t inc0 = n0;
    #pragma unroll
    for (int off = 1; off < 64; off <<= 1) {
      uint32_t u = __shfl_up(inc0, off);
      if (l >= off) inc0 += u;
    }
    uint32_t T0 = __shfl(inc0, 63);
    uint32_t ex0 = inc0 - n0;
    uint32_t n1 = (uint32_t)__popcll(v1);
    uint32_t inc1 = n1;
    #pragma unroll
    for (int off = 1; off < 64; off <<= 1) {
      uint32_t u = __shfl_up(inc1, off);
      if (l >= off) inc1 += u;
    }
    uint32_t T1 = __shfl(inc1, 63);
    uint32_t ex1 = T0 + inc1 - n1;
    uint32_t TV = T0 + T1;
    if (cnt >= POST_NMS_ || TV == 0) break;
    uint32_t m = (TV < KB) ? TV : KB;

    // ---- extract first m valid candidate indices into cslot ----
    __syncthreads();
    if (l < KB) cslot[l] = 0;
    __syncthreads();
    if (ex0 < KB) {
      unsigned long long w = v0; uint32_t r = ex0;
      while (w && r < KB) { int b = __ffsll(w) - 1; cslot[r] = l * 64 + b; ++r; w &= w - 1; }
    }
    if (ex1 < KB && v1) {
      unsigned long long w = v1; uint32_t r = ex1;
      while (w && r < KB) { int b = __ffsll(w) - 1; cslot[r] = (64 + l) * 64 + b; ++r; w &= w - 1; }
    }
    __syncthreads();

    // ---- parallel row loads for the m candidates ----
#define ROWDECL(k) uint64_t rm0_##k = 0, rm1_##k = 0;
    FOR16(ROWDECL)
#undef ROWDECL
#define ROWLOAD(k) if (k < (int)m) { const uint64_t* p = M + (size_t)cslot[k] * NWORD; \
                     rm0_##k = p[l]; rm1_##k = (l < 32) ? p[64 + l] : 0ull; }
    FOR16(ROWLOAD)
#undef ROWLOAD
    // box prefetch: lane k holds candidate k's output box
    float4 obox = make_float4(0.f, 0.f, 0.f, 0.f);
    if (l < KB) obox = sobox[cslot[l]];

    // ---- build S[k][j] = M[ck][cj] as uniform 16-bit rows via shfl+ballot ----
    uint32_t cj = (l < KB) ? (uint32_t)cslot[l] : 0u;
    uint32_t wj = cj >> 6, bj = cj & 63;
    int srcA = (int)(wj & 63), srcB = (int)(wj & 31);
    uint32_t srow[KB];
#define SROW(k) { uint64_t a = __shfl((unsigned long long)rm0_##k, srcA); \
                  uint64_t b = __shfl((unsigned long long)rm1_##k, srcB); \
                  uint64_t sel = (wj < 64) ? a : b; \
                  uint32_t bit = (l < KB && k < (int)m) ? (uint32_t)((sel >> bj) & 1) : 0u; \
                  srow[k] = (uint32_t)(__ballot(bit) & 0xFFFFull); }
    FOR16(SROW)
#undef SROW

    // ---- exact greedy resolve over the m candidates (uniform scalar) ----
    uint32_t cnt0 = cnt;
    uint32_t wm = 0, supp = 0;
    #pragma unroll
    for (int k = 0; k < KB; ++k) {
      if (k < (int)m && cnt < POST_NMS_ && !((supp >> k) & 1)) {
        wm |= 1u << k; ++cnt; supp |= srow[k];
      }
    }

    // ---- write winner boxes in order ----
    if (l < KB && ((wm >> l) & 1)) {
      uint32_t pos = cnt0 + (uint32_t)__popc(wm & ((1u << l) - 1));
      *(float4*)(out + (size_t)pos * 4) = obox;
    }

    // ---- apply combined suppression ----
    uint64_t comb0 = 0, comb1 = 0;
#define COMB(k) if ((wm >> k) & 1) { comb0 |= rm0_##k; comb1 |= rm1_##k; }
    FOR16(COMB)
#undef COMB
    v0 &= ~comb0; v1 &= ~comb1;
  }

  // zero-fill remaining output rows
  for (int j = l; j < (int)(POST_NMS_ - cnt) * 4; j += 64) out[cnt * 4 + j] = 0.0f;
}

// ---------- launch ----------
extern "C" void kernel_launch(void* const* d_in, const int* in_sizes, int n_in,
                              void* d_out, int out_size, void* d_ws, size_t ws_size,
                              hipStream_t stream) {
  const float*  scores  = (const float*)d_in[0];
  const float4* deltas  = (const float4*)d_in[1];
  const float4* anchors = (const float4*)d_in[2];
  float* out = (float*)d_out;

  uint8_t* w8 = (uint8_t*)d_ws;
  // region 0: d[] (5,308,416 B), live k_hA..k_gather; then overlaid by M + sorted-box arrays
  uint32_t* darr  = (uint32_t*)w8;
  uint64_t* M     = (uint64_t*)w8;                          // 4,718,592
  float4*   sbox4 = (float4*)(w8 + 4718592);                //  98,304
  float*    sarea = (float*) (w8 + 4816896);                //  24,576
  float4*   sobox = (float4*)(w8 + 4841472);                //  98,304 -> 4,939,776 < 5,308,416
  // region 1 (fresh): @5,308,416
  uint64_t* keyhi  = (uint64_t*)(w8 + 5308416);             //  49,152
  uint32_t* keylo  = (uint32_t*)(w8 + 5357568);             //  24,576
  float4*   box4u  = (float4*)  (w8 + 5382144);             //  98,304
  uint32_t* rank2d = (uint32_t*)(w8 + 5480448);             // 196,608 -> 5,677,056
  // region 2: persistent small (hist+ctr+valid contiguous for single memset)
  uint32_t* hist = (uint32_t*)(w8 + 5677056);               //   1,024
  uint32_t* ctr  = (uint32_t*)(w8 + 5678080);               //      64
  unsigned long long* valid = (unsigned long long*)(w8 + 5678144); // 1,024
  uint64_t* L    = (uint64_t*)(w8 + 5679168);               //  48,000
  uint64_t* Lb   = (uint64_t*)(w8 + 5727168);               //  32,768 -> 5,759,936 total

  const uint4* dv = (const uint4*)darr;

  hipMemsetAsync(hist, 0, 2112, stream);     // hist + ctr + valid

  k_hA   <<<NB, 256, 0, stream>>>(scores, deltas, anchors, darr, hist);
  k_pick8<<<1, 64, 0, stream>>>(hist, ctr, 4);
  k_hBC  <<<NB, 256, 0, stream>>>(dv, ctr, hist, 2);
  k_pick8<<<1, 64, 0, stream>>>(hist, ctr, 5);
  k_hBC  <<<NB, 256, 0, stream>>>(dv, ctr, hist, 3);
  k_pick8<<<1, 64, 0, stream>>>(hist, ctr, 6);
  k_gather <<<NB, 256, 0, stream>>>(dv, ctr, L, Lb);
  k_rankb  <<<1, 256, 0, stream>>>(ctr, Lb, L);
  k_prep   <<<NPAD / 256, 256, 0, stream>>>(L, deltas, anchors, keyhi, keylo, box4u);
  k_rank   <<<192, 256, 0, stream>>>(keyhi, keylo, rank2d);
  k_scatter<<<NPAD / 256, 256, 0, stream>>>(keyhi, rank2d, box4u, sbox4, sarea, sobox, valid);
  k_mat    <<<192, 512, 0, stream>>>(sbox4, sarea, M);
  k_seq    <<<1, 64, 0, stream>>>(valid, M, sobox, out);
}